// Round 1
// baseline (606.079 us; speedup 1.0000x reference)
//
#include <hip/hip_runtime.h>
#include <hip/hip_bf16.h>
#include <cstdint>

using bf16 = __hip_bfloat16;
typedef __bf16 bf16x8 __attribute__((ext_vector_type(8)));
typedef float f32x4 __attribute__((ext_vector_type(4)));

#define DEV static __device__ __forceinline__

DEV float toF(float x) { return x; }
DEV float toF(bf16 x) { return __bfloat162float(x); }

// async global->LDS, 16B per lane. LDS dest = wave-uniform base + lane*16.
DEV void gload_lds16(const void* g, void* l) {
  __builtin_amdgcn_global_load_lds(
      (const __attribute__((address_space(1))) unsigned int*)g,
      (__attribute__((address_space(3))) unsigned int*)l, 16, 0, 0);
}

// C[m][n] = alpha * sum_k A[m][k] * BT[n][k]  (+ bias[m])
// A: bf16 row-major [M][lda], BT: bf16 row-major [N][ldb] (i.e. B transposed)
// per-z batch strides sA/sB/sC in elements. 256 threads, 4 waves (2x2),
// 16x16x32 bf16 MFMA, BK=32, global_load_lds staging (m97 pattern).
template <int BM, int BN, bool OUT_BF16>
__launch_bounds__(256, 2)
__global__ void gemm_bt(const bf16* __restrict__ A, long long sA,
                        const bf16* __restrict__ B, long long sB,
                        void* __restrict__ Cv, long long sC,
                        const float* __restrict__ bias,
                        int K, int lda, int ldb, int ldc, float alpha) {
  constexpr int BK = 32;
  __shared__ bf16 ldsA[BM * BK];
  __shared__ bf16 ldsB[BN * BK];
  const int tid = threadIdx.x;
  const int wave = tid >> 6, lane = tid & 63;
  const long long z = blockIdx.z;
  A += z * sA;
  B += z * sB;
  const int m0 = blockIdx.y * BM, n0 = blockIdx.x * BN;

  constexpr int WM = BM / 2, WN = BN / 2;   // wave tile
  constexpr int MR = WM / 16, NR = WN / 16; // 16x16 frags per wave
  const int wm = (wave >> 1) * WM, wn = (wave & 1) * WN;
  const int lrow = lane & 15;
  const int kb = (lane >> 4) * 8;

  f32x4 acc[MR][NR] = {};

  for (int k0 = 0; k0 < K; k0 += BK) {
    // stage A tile [BM][32] bf16 -> linear LDS; 16B chunks, 4 chunks/row
#pragma unroll
    for (int r = 0; r < BM / 64; ++r) {
      int c = r * 256 + tid;
      int row = c >> 2, sub = c & 3;
      gload_lds16(A + (long long)(m0 + row) * lda + k0 + sub * 8,
                  (void*)(ldsA + (r * 256 + wave * 64) * 8));
    }
#pragma unroll
    for (int r = 0; r < BN / 64; ++r) {
      int c = r * 256 + tid;
      int row = c >> 2, sub = c & 3;
      gload_lds16(B + (long long)(n0 + row) * ldb + k0 + sub * 8,
                  (void*)(ldsB + (r * 256 + wave * 64) * 8));
    }
    __syncthreads(); // compiler drains vmcnt before s_barrier

    bf16x8 af[MR], bfr[NR];
#pragma unroll
    for (int i = 0; i < MR; ++i)
      af[i] = *(const bf16x8*)&ldsA[(wm + i * 16 + lrow) * BK + kb];
#pragma unroll
    for (int j = 0; j < NR; ++j)
      bfr[j] = *(const bf16x8*)&ldsB[(wn + j * 16 + lrow) * BK + kb];
#pragma unroll
    for (int i = 0; i < MR; ++i)
#pragma unroll
      for (int j = 0; j < NR; ++j)
        acc[i][j] =
            __builtin_amdgcn_mfma_f32_16x16x32_bf16(af[i], bfr[j], acc[i][j], 0, 0, 0);
    __syncthreads();
  }

  const int r4 = (lane >> 4) * 4;
#pragma unroll
  for (int i = 0; i < MR; ++i) {
#pragma unroll
    for (int j = 0; j < NR; ++j) {
#pragma unroll
      for (int r = 0; r < 4; ++r) {
        int grow = m0 + wm + i * 16 + r4 + r;
        int gcol = n0 + wn + j * 16 + lrow;
        float vv = acc[i][j][r] * alpha;
        if (bias) vv += bias[grow];
        if constexpr (OUT_BF16)
          ((bf16*)Cv)[z * sC + (long long)grow * ldc + gcol] = __float2bfloat16(vv);
        else
          ((float*)Cv)[z * sC + (long long)grow * ldc + gcol] = vv;
      }
    }
  }
}

// softmax over 16 heads at each (m,m') of one batch; score f32 [16][1024][1024]
__global__ void softmax_heads(const float* __restrict__ score, bf16* __restrict__ P) {
  const size_t idx = (size_t)blockIdx.x * 256 + threadIdx.x; // (m,m') flat, 1M
  float s[16];
  float mx = -INFINITY;
#pragma unroll
  for (int h = 0; h < 16; ++h) {
    s[h] = score[(size_t)h * 1048576 + idx];
    mx = fmaxf(mx, s[h]);
  }
  float sum = 0.f;
#pragma unroll
  for (int h = 0; h < 16; ++h) {
    s[h] = __expf(s[h] - mx);
    sum += s[h];
  }
  const float inv = 1.0f / sum;
#pragma unroll
  for (int h = 0; h < 16; ++h)
    P[(size_t)h * 1048576 + idx] = __float2bfloat16(s[h] * inv);
}

// out[c][r] = (bf16) in[r][c]; in is [R][C] per batch z (TIN = float or bf16)
template <typename TIN>
__global__ void transpose_tile(const TIN* __restrict__ in, bf16* __restrict__ out,
                               int R, int C, long long sIn, long long sOut) {
  __shared__ float t[32][33];
  const long long z = blockIdx.z;
  in += z * sIn;
  out += z * sOut;
  const int r0 = blockIdx.y * 32, c0 = blockIdx.x * 32;
  const int tx = threadIdx.x, ty = threadIdx.y; // (32, 8)
#pragma unroll
  for (int i = ty; i < 32; i += 8)
    t[i][tx] = toF(in[(long long)(r0 + i) * C + c0 + tx]);
  __syncthreads();
#pragma unroll
  for (int i = ty; i < 32; i += 8)
    out[(long long)(c0 + i) * R + r0 + tx] = __float2bfloat16(t[tx][i]);
}

__global__ void cast_f32_bf16(const float* __restrict__ in, bf16* __restrict__ out, int n) {
  int i = (blockIdx.x * 256 + threadIdx.x) * 4;
  if (i + 3 < n) {
    float4 f = *(const float4*)(in + i);
    out[i + 0] = __float2bfloat16(f.x);
    out[i + 1] = __float2bfloat16(f.y);
    out[i + 2] = __float2bfloat16(f.z);
    out[i + 3] = __float2bfloat16(f.w);
  }
}

extern "C" void kernel_launch(void* const* d_in, const int* in_sizes, int n_in,
                              void* d_out, int out_size, void* d_ws, size_t ws_size,
                              hipStream_t stream) {
  (void)in_sizes; (void)n_in; (void)out_size;
  const float* q  = (const float*)d_in[0];
  const float* k  = (const float*)d_in[1];
  const float* v  = (const float*)d_in[2];
  const float* Wq = (const float*)d_in[3];
  const float* bq = (const float*)d_in[4];
  const float* Wk = (const float*)d_in[5];
  const float* bk = (const float*)d_in[6];
  const float* Wv = (const float*)d_in[7];
  const float* bv = (const float*)d_in[8];
  const float* Wo = (const float*)d_in[9];
  const float* bo = (const float*)d_in[10];
  float* out = (float*)d_out;

  const size_t MB = 1ull << 20;
  if (ws_size < 178 * MB) return; // need 178 MiB scratch
  char* ws = (char*)d_ws;
  // persistent
  bf16* qp    = (bf16*)(ws + 0 * MB);   // [B][1024][1024]
  bf16* kpT   = (bf16*)(ws + 16 * MB);  // [B][l][o]
  bf16* vpT   = (bf16*)(ws + 32 * MB);  // [B][16][64][1024] per-head V^T
  bf16* aout  = (bf16*)(ws + 48 * MB);  // [B][o][l]
  bf16* aoutT = (bf16*)(ws + 64 * MB);  // [B][l][o]
  bf16* WoB   = (bf16*)(ws + 80 * MB);
  // phase-1 scratch (dead before phase 2)
  char* scr = ws + 82 * MB;
  bf16* WqB = (bf16*)(scr + 0 * MB);
  bf16* WkB = (bf16*)(scr + 2 * MB);
  bf16* WvB = (bf16*)(scr + 4 * MB);
  bf16* qT  = (bf16*)(scr + 6 * MB);
  bf16* kT  = (bf16*)(scr + 22 * MB);
  bf16* vT  = (bf16*)(scr + 38 * MB);
  bf16* kp  = (bf16*)(scr + 54 * MB);
  bf16* vp  = (bf16*)(scr + 70 * MB);
  // phase-2 scratch (per-b, reused)
  float* score = (float*)(scr + 0 * MB); // [16][1024][1024] f32 = 64 MB
  bf16*  P     = (bf16*)(scr + 64 * MB); // [16][1024][1024] bf16 = 32 MB

  const long long M1 = 1048576, HB = 65536;
  dim3 tb(32, 8);

  // weight casts
  cast_f32_bf16<<<1024, 256, 0, stream>>>(Wq, WqB, 1 << 20);
  cast_f32_bf16<<<1024, 256, 0, stream>>>(Wk, WkB, 1 << 20);
  cast_f32_bf16<<<1024, 256, 0, stream>>>(Wv, WvB, 1 << 20);
  cast_f32_bf16<<<1024, 256, 0, stream>>>(Wo, WoB, 1 << 20);
  // input transpose+cast: q[b][c][l] -> qT[b][l][c] (B^T operand for proj)
  transpose_tile<float><<<dim3(32, 32, 8), tb, 0, stream>>>(q, qT, 1024, 1024, M1, M1);
  transpose_tile<float><<<dim3(32, 32, 8), tb, 0, stream>>>(k, kT, 1024, 1024, M1, M1);
  transpose_tile<float><<<dim3(32, 32, 8), tb, 0, stream>>>(v, vT, 1024, 1024, M1, M1);
  // projections: qp[o][l] = Wq[o][c] . qT[l][c]  (+bias)
  gemm_bt<128, 128, true><<<dim3(8, 8, 8), 256, 0, stream>>>(
      WqB, 0, qT, M1, qp, M1, bq, 1024, 1024, 1024, 1024, 1.0f);
  gemm_bt<128, 128, true><<<dim3(8, 8, 8), 256, 0, stream>>>(
      WkB, 0, kT, M1, kp, M1, bk, 1024, 1024, 1024, 1024, 1.0f);
  gemm_bt<128, 128, true><<<dim3(8, 8, 8), 256, 0, stream>>>(
      WvB, 0, vT, M1, vp, M1, bv, 1024, 1024, 1024, 1024, 1.0f);
  // kpT[b][l][o] = kp[b][o][l]
  transpose_tile<bf16><<<dim3(32, 32, 8), tb, 0, stream>>>(kp, kpT, 1024, 1024, M1, M1);
  // per-(b,h) V^T: vp block [1024 m'][64 d] -> vpT [64 d][1024 m']
  transpose_tile<bf16><<<dim3(2, 32, 128), tb, 0, stream>>>(vp, vpT, 1024, 64, HB, HB);

  for (int bb = 0; bb < 8; ++bb) {
    // score[h][m][m'] = 1/8 * Qh[m][d] . Kt[d][m'];  A=qp head block [1024][64],
    // BT = kpT rows m' with k-offset h*64
    gemm_bt<128, 128, false><<<dim3(8, 8, 16), 256, 0, stream>>>(
        qp + (long long)bb * M1, HB,
        kpT + (long long)bb * M1, 64,
        score, M1, nullptr, 64, 64, 1024, 1024, 0.125f);
    softmax_heads<<<4096, 256, 0, stream>>>(score, P);
    // out[m][d] = P[m][m'] . V[m'][d];  BT = vpT[h] ([64 d][1024 m'])
    gemm_bt<64, 64, true><<<dim3(1, 16, 16), 256, 0, stream>>>(
        P, M1,
        vpT + (long long)bb * 16 * HB, HB,
        aout + (long long)bb * 16 * HB, HB, nullptr, 1024, 1024, 1024, 64, 1.0f);
  }

  // aoutT[b][l][o] = aout[b][o][l]
  transpose_tile<bf16><<<dim3(32, 32, 8), tb, 0, stream>>>(aout, aoutT, 1024, 1024, M1, M1);
  // result[o'][l] = Wo[o'][o] . aout[o][l] + bo  (f32 to d_out)
  gemm_bt<128, 128, false><<<dim3(8, 8, 8), 256, 0, stream>>>(
      WoB, 0, aoutT, M1, out, M1, bo, 1024, 1024, 1024, 1024, 1.0f);
}

// Round 2
// 398.478 us; speedup vs baseline: 1.5210x; 1.5210x over previous
//
#include <hip/hip_runtime.h>
#include <hip/hip_bf16.h>
#include <cstdint>

using bf16 = __hip_bfloat16;
typedef __bf16 bf16x8 __attribute__((ext_vector_type(8)));
typedef float f32x4 __attribute__((ext_vector_type(4)));

#define DEV static __device__ __forceinline__

DEV float toF(float x) { return x; }
DEV float toF(bf16 x) { return __bfloat162float(x); }

// async global->LDS, 16B per lane. LDS dest = wave-uniform base + lane*16.
DEV void gload_lds16(const void* g, void* l) {
  __builtin_amdgcn_global_load_lds(
      (const __attribute__((address_space(1))) unsigned int*)g,
      (__attribute__((address_space(3))) unsigned int*)l, 16, 0, 0);
}

// C[m][n] = alpha * sum_k A[m][k] * BT[n][k]  (+ bias[m] or bias[n])
template <int BM, int BN, bool OUT_BF16, bool BIAS_COL>
__launch_bounds__(256, 2)
__global__ void gemm_bt(const bf16* __restrict__ A, long long sA,
                        const bf16* __restrict__ B, long long sB,
                        void* __restrict__ Cv, long long sC,
                        const float* __restrict__ bias,
                        int K, int lda, int ldb, int ldc, float alpha) {
  constexpr int BK = 32;
  __shared__ bf16 ldsA[BM * BK];
  __shared__ bf16 ldsB[BN * BK];
  const int tid = threadIdx.x;
  const int wave = tid >> 6, lane = tid & 63;
  const long long z = blockIdx.z;
  A += z * sA;
  B += z * sB;
  const int m0 = blockIdx.y * BM, n0 = blockIdx.x * BN;

  constexpr int WM = BM / 2, WN = BN / 2;
  constexpr int MR = WM / 16, NR = WN / 16;
  const int wm = (wave >> 1) * WM, wn = (wave & 1) * WN;
  const int lrow = lane & 15;
  const int kb = (lane >> 4) * 8;

  f32x4 acc[MR][NR] = {};

  for (int k0 = 0; k0 < K; k0 += BK) {
#pragma unroll
    for (int r = 0; r < BM / 64; ++r) {
      int c = r * 256 + tid;
      int row = c >> 2, sub = c & 3;
      gload_lds16(A + (long long)(m0 + row) * lda + k0 + sub * 8,
                  (void*)(ldsA + (r * 256 + wave * 64) * 8));
    }
#pragma unroll
    for (int r = 0; r < BN / 64; ++r) {
      int c = r * 256 + tid;
      int row = c >> 2, sub = c & 3;
      gload_lds16(B + (long long)(n0 + row) * ldb + k0 + sub * 8,
                  (void*)(ldsB + (r * 256 + wave * 64) * 8));
    }
    __syncthreads();

    bf16x8 af[MR], bfr[NR];
#pragma unroll
    for (int i = 0; i < MR; ++i)
      af[i] = *(const bf16x8*)&ldsA[(wm + i * 16 + lrow) * BK + kb];
#pragma unroll
    for (int j = 0; j < NR; ++j)
      bfr[j] = *(const bf16x8*)&ldsB[(wn + j * 16 + lrow) * BK + kb];
#pragma unroll
    for (int i = 0; i < MR; ++i)
#pragma unroll
      for (int j = 0; j < NR; ++j)
        acc[i][j] =
            __builtin_amdgcn_mfma_f32_16x16x32_bf16(af[i], bfr[j], acc[i][j], 0, 0, 0);
    __syncthreads();
  }

  const int r4 = (lane >> 4) * 4;
#pragma unroll
  for (int i = 0; i < MR; ++i) {
#pragma unroll
    for (int j = 0; j < NR; ++j) {
#pragma unroll
      for (int r = 0; r < 4; ++r) {
        int grow = m0 + wm + i * 16 + r4 + r;
        int gcol = n0 + wn + j * 16 + lrow;
        float vv = acc[i][j][r] * alpha;
        if (bias) vv += BIAS_COL ? bias[gcol] : bias[grow];
        if constexpr (OUT_BF16)
          ((bf16*)Cv)[z * sC + (long long)grow * ldc + gcol] = __float2bfloat16(vv);
        else
          ((float*)Cv)[z * sC + (long long)grow * ldc + gcol] = vv;
      }
    }
  }
}

// h-slot swizzle for the score LDS buffer: bijective in h for fixed (m,mm);
// spreads score C-frag b32 stores across banks (~2-way instead of 32-way).
DEV int slotmask(int m, int mm) {
  return (((mm & 7) << 1) ^ (((m >> 2) & 3) << 1) ^ ((mm >> 3) & 1));
}

// Fused score (QK^T/8) -> softmax over 16 heads -> PV, per (batch, 32-row m-tile).
// 8 waves, 2 heads/wave. qp: per-batch contiguous head blocks [16][1024 m][64 d];
// kpT: [1024 m'][1024 o]; vpT: per batch [16][64 d][1024 m']; aout flat (h,m,d).
__launch_bounds__(512, 2)
__global__ void fused_attn(const bf16* __restrict__ qp,
                           const bf16* __restrict__ kpT,
                           const bf16* __restrict__ vpT,
                           bf16* __restrict__ aout) {
  __shared__ float S[1024 * 16];     // [p=m*32+mm][slot] 64KB
  __shared__ bf16 Pl[16 * 32 * 40];  // [h][m][mm stride40] 40KB
  const int bid = blockIdx.x;
  const int bb = bid & 7, mt = bid >> 3;  // batch -> XCD for K/V L2 residency
  const int m0 = mt * 32;
  const int tid = threadIdx.x;
  const int wave = tid >> 6, lane = tid & 63;
  const int lrow = lane & 15, kb8 = (lane >> 4) * 8, r4 = (lane >> 4) * 4;
  const int h0 = wave * 2;

  const bf16* Qb = qp + ((size_t)bb << 20);
  const bf16* Kb = kpT + ((size_t)bb << 20);
  const bf16* Vb = vpT + ((size_t)bb << 20);
  bf16* Ob = aout + ((size_t)bb << 20);

  // hoist Q fragments: A[m][dd], rows contiguous per head block
  bf16x8 qf[2][2][2];
#pragma unroll
  for (int h = 0; h < 2; ++h)
#pragma unroll
    for (int mi = 0; mi < 2; ++mi)
#pragma unroll
      for (int kc = 0; kc < 2; ++kc)
        qf[h][mi][kc] = *(const bf16x8*)(Qb + ((size_t)(h0 + h) << 16) +
                                         (m0 + mi * 16 + lrow) * 64 + kc * 32 + kb8);

  f32x4 oacc[2][2][4] = {};

  for (int t = 0; t < 32; ++t) {
    const int n0 = t * 32;
    // ---- score: S[h][m][mm] = QK^T / 8 ----
    f32x4 sacc[2][2][2] = {};
#pragma unroll
    for (int h = 0; h < 2; ++h) {
#pragma unroll
      for (int kc = 0; kc < 2; ++kc) {
        bf16x8 kf0 = *(const bf16x8*)(Kb + (size_t)(n0 + lrow) * 1024 +
                                      ((h0 + h) << 6) + kc * 32 + kb8);
        bf16x8 kf1 = *(const bf16x8*)(Kb + (size_t)(n0 + 16 + lrow) * 1024 +
                                      ((h0 + h) << 6) + kc * 32 + kb8);
#pragma unroll
        for (int mi = 0; mi < 2; ++mi) {
          sacc[h][mi][0] = __builtin_amdgcn_mfma_f32_16x16x32_bf16(
              qf[h][mi][kc], kf0, sacc[h][mi][0], 0, 0, 0);
          sacc[h][mi][1] = __builtin_amdgcn_mfma_f32_16x16x32_bf16(
              qf[h][mi][kc], kf1, sacc[h][mi][1], 0, 0, 0);
        }
      }
    }
#pragma unroll
    for (int h = 0; h < 2; ++h)
#pragma unroll
      for (int mi = 0; mi < 2; ++mi)
#pragma unroll
        for (int nj = 0; nj < 2; ++nj)
#pragma unroll
          for (int r = 0; r < 4; ++r) {
            int m = mi * 16 + r4 + r;
            int mm = nj * 16 + lrow;
            int s = (h0 + h) ^ slotmask(m, mm);
            S[(m * 32 + mm) * 16 + s] = sacc[h][mi][nj][r] * 0.125f;
          }
    __syncthreads();
    // ---- softmax over heads (elementwise in (m,mm)) ----
#pragma unroll
    for (int pi = 0; pi < 2; ++pi) {
      int p = tid + pi * 512;
      const float4* row = (const float4*)&S[p * 16];
      float4 a0 = row[0], a1 = row[1], a2 = row[2], a3 = row[3];
      float vals[16] = {a0.x, a0.y, a0.z, a0.w, a1.x, a1.y, a1.z, a1.w,
                        a2.x, a2.y, a2.z, a2.w, a3.x, a3.y, a3.z, a3.w};
      float mx = vals[0];
#pragma unroll
      for (int s = 1; s < 16; ++s) mx = fmaxf(mx, vals[s]);
      float sum = 0.f;
#pragma unroll
      for (int s = 0; s < 16; ++s) {
        vals[s] = __expf(vals[s] - mx);
        sum += vals[s];
      }
      float inv = 1.0f / sum;
      int m = p >> 5, mm = p & 31, msk = slotmask(m, mm);
#pragma unroll
      for (int s = 0; s < 16; ++s)
        Pl[(s ^ msk) * 1280 + m * 40 + mm] = __float2bfloat16(vals[s] * inv);
    }
    __syncthreads();
    // ---- PV: oacc[h][m][d] += P[m][mm] * V[mm][d] ----
#pragma unroll
    for (int h = 0; h < 2; ++h) {
      bf16x8 pa0 = *(const bf16x8*)&Pl[(h0 + h) * 1280 + lrow * 40 + kb8];
      bf16x8 pa1 = *(const bf16x8*)&Pl[(h0 + h) * 1280 + (16 + lrow) * 40 + kb8];
#pragma unroll
      for (int dj = 0; dj < 4; ++dj) {
        bf16x8 vf = *(const bf16x8*)(Vb + (size_t)((h0 + h) * 64 + dj * 16 + lrow) * 1024 +
                                     n0 + kb8);
        oacc[h][0][dj] = __builtin_amdgcn_mfma_f32_16x16x32_bf16(pa0, vf, oacc[h][0][dj], 0, 0, 0);
        oacc[h][1][dj] = __builtin_amdgcn_mfma_f32_16x16x32_bf16(pa1, vf, oacc[h][1][dj], 0, 0, 0);
      }
    }
    __syncthreads();
  }
  // ---- write out: flat (h, m, d) ----
#pragma unroll
  for (int h = 0; h < 2; ++h)
#pragma unroll
    for (int mi = 0; mi < 2; ++mi)
#pragma unroll
      for (int dj = 0; dj < 4; ++dj)
#pragma unroll
        for (int r = 0; r < 4; ++r)
          Ob[((size_t)(h0 + h) << 16) + (size_t)(m0 + mi * 16 + r4 + r) * 64 +
             dj * 16 + lrow] = __float2bfloat16(oacc[h][mi][dj][r]);
}

// out[c][r] = (bf16) in[r][c]
template <typename TIN>
__global__ void transpose_tile(const TIN* __restrict__ in, bf16* __restrict__ out,
                               int R, int C, long long sIn, long long sOut) {
  __shared__ float t[32][33];
  const long long z = blockIdx.z;
  in += z * sIn;
  out += z * sOut;
  const int r0 = blockIdx.y * 32, c0 = blockIdx.x * 32;
  const int tx = threadIdx.x, ty = threadIdx.y;
#pragma unroll
  for (int i = ty; i < 32; i += 8)
    t[i][tx] = toF(in[(long long)(r0 + i) * C + c0 + tx]);
  __syncthreads();
#pragma unroll
  for (int i = ty; i < 32; i += 8)
    out[(long long)(c0 + i) * R + r0 + tx] = __float2bfloat16(t[tx][i]);
}

__global__ void cast_f32_bf16(const float* __restrict__ in, bf16* __restrict__ out, int n) {
  int i = (blockIdx.x * 256 + threadIdx.x) * 4;
  if (i + 3 < n) {
    float4 f = *(const float4*)(in + i);
    out[i + 0] = __float2bfloat16(f.x);
    out[i + 1] = __float2bfloat16(f.y);
    out[i + 2] = __float2bfloat16(f.z);
    out[i + 3] = __float2bfloat16(f.w);
  }
}

extern "C" void kernel_launch(void* const* d_in, const int* in_sizes, int n_in,
                              void* d_out, int out_size, void* d_ws, size_t ws_size,
                              hipStream_t stream) {
  (void)in_sizes; (void)n_in; (void)out_size;
  const float* q  = (const float*)d_in[0];
  const float* k  = (const float*)d_in[1];
  const float* v  = (const float*)d_in[2];
  const float* Wq = (const float*)d_in[3];
  const float* bq = (const float*)d_in[4];
  const float* Wk = (const float*)d_in[5];
  const float* bk = (const float*)d_in[6];
  const float* Wv = (const float*)d_in[7];
  const float* bv = (const float*)d_in[8];
  const float* Wo = (const float*)d_in[9];
  const float* bo = (const float*)d_in[10];
  float* out = (float*)d_out;

  const size_t MB = 1ull << 20;
  if (ws_size < 152 * MB) return;
  char* ws = (char*)d_ws;
  bf16* qp    = (bf16*)(ws + 0 * MB);   // [B][16][1024][64] head-blocked
  bf16* kpT   = (bf16*)(ws + 16 * MB);  // [B][1024 m'][1024 o]
  bf16* vpT   = (bf16*)(ws + 32 * MB);  // [B][16][64][1024]
  bf16* aout  = (bf16*)(ws + 48 * MB);  // [B] flat (h,m,d) == [o][l]
  bf16* aoutT = (bf16*)(ws + 64 * MB);  // [B][l][o]
  bf16* WoB   = (bf16*)(ws + 80 * MB);
  char* scr = ws + 82 * MB;
  bf16* WqB = (bf16*)(scr + 0 * MB);
  bf16* WkB = (bf16*)(scr + 2 * MB);
  bf16* WvB = (bf16*)(scr + 4 * MB);
  bf16* qT  = (bf16*)(scr + 6 * MB);
  bf16* kT  = (bf16*)(scr + 22 * MB);
  bf16* vT  = (bf16*)(scr + 38 * MB);
  bf16* vp  = (bf16*)(scr + 54 * MB);

  const long long M1 = 1048576, HB = 65536;
  dim3 tb(32, 8);

  cast_f32_bf16<<<1024, 256, 0, stream>>>(Wq, WqB, 1 << 20);
  cast_f32_bf16<<<1024, 256, 0, stream>>>(Wk, WkB, 1 << 20);
  cast_f32_bf16<<<1024, 256, 0, stream>>>(Wv, WvB, 1 << 20);
  cast_f32_bf16<<<1024, 256, 0, stream>>>(Wo, WoB, 1 << 20);
  transpose_tile<float><<<dim3(32, 32, 8), tb, 0, stream>>>(q, qT, 1024, 1024, M1, M1);
  transpose_tile<float><<<dim3(32, 32, 8), tb, 0, stream>>>(k, kT, 1024, 1024, M1, M1);
  transpose_tile<float><<<dim3(32, 32, 8), tb, 0, stream>>>(v, vT, 1024, 1024, M1, M1);
  // qp[o][l] = Wq . q  (bias rows)
  gemm_bt<128, 128, true, false><<<dim3(8, 8, 8), 256, 0, stream>>>(
      WqB, 0, qT, M1, qp, M1, bq, 1024, 1024, 1024, 1024, 1.0f);
  // kpT[l][o] = (Wk . k)^T directly: A=kT, BT=WkB, bias cols
  gemm_bt<128, 128, true, true><<<dim3(8, 8, 8), 256, 0, stream>>>(
      kT, M1, WkB, 0, kpT, M1, bk, 1024, 1024, 1024, 1024, 1.0f);
  gemm_bt<128, 128, true, false><<<dim3(8, 8, 8), 256, 0, stream>>>(
      WvB, 0, vT, M1, vp, M1, bv, 1024, 1024, 1024, 1024, 1.0f);
  // per-(b,h) V^T: [1024 m'][64 d] -> [64 d][1024 m']
  transpose_tile<bf16><<<dim3(2, 32, 128), tb, 0, stream>>>(vp, vpT, 1024, 64, HB, HB);

  fused_attn<<<dim3(256), 512, 0, stream>>>(qp, kpT, vpT, aout);

  transpose_tile<bf16><<<dim3(32, 32, 8), tb, 0, stream>>>(aout, aoutT, 1024, 1024, M1, M1);
  gemm_bt<128, 128, false, false><<<dim3(8, 8, 8), 256, 0, stream>>>(
      WoB, 0, aoutT, M1, out, M1, bo, 1024, 1024, 1024, 1024, 1.0f);
}